// Round 19
// baseline (451.005 us; speedup 1.0000x reference)
//
#include <hip/hip_runtime.h>
#include <math.h>

#define PI_D 3.14159265358979323846

constexpr int NBATCH = 8;
constexpr int NPTS   = 2048;
constexpr int F1C    = 100;
constexpr int F2C    = 100;

__host__ __device__ constexpr int S2c(int l){ return l*(2*l-1)*(2*l+1)/3; }

// ---- workspace layout (float offsets) ----
constexpr int OFF_WIN   = 0;
constexpr int OFF_WMID  = OFF_WIN + 60;
constexpr int OFF_WOUTQ = OFF_WMID + 32;
constexpr int OFF_DM0W  = OFF_WOUTQ + 20;
constexpr int OFF_DMID  = OFF_DM0W + 60*256;
constexpr int OFF_DOUT  = OFF_DMID + 32*S2c(16);
constexpr int OFF_DEQ   = OFF_DOUT + 20*S2c(10);
constexpr int OFF_IMG   = OFF_DEQ + S2c(16);
constexpr int OFF_XF    = OFF_IMG + NBATCH*60*60;
constexpr int OFF_XHAT  = OFF_XF + NBATCH*60*31*2;
constexpr int OFF_WS2   = OFF_XHAT + NBATCH*256*2;
constexpr int OFF_BN1   = OFF_WS2 + 100*31*2;
constexpr int OFF_BN1AB = OFF_BN1 + 200;
constexpr int OFF_BN2   = OFF_BN1AB + 200;
constexpr int OFF_BN2AB = OFF_BN2 + 200;
constexpr int OFF_LUTA  = OFF_BN2AB + 200;
constexpr int OFF_LUTB  = OFF_LUTA + 1330;
constexpr int OFF_LUTC  = OFF_LUTB + 1330;
constexpr int OFF_GT    = OFF_LUTC + 1330;            // 34: Gtot[31], Htot r/i
constexpr int OFF_WCONV = OFF_GT + 34;                // W[i][o][ni][2]
constexpr int OFF_XHAT2 = OFF_WCONV + 100*100*19*2;
constexpr int OFF_SBUF  = OFF_XHAT2 + NBATCH*100*S2c(10)*2;  // S[b][i][q][2]
constexpr int OFF_ZHAT2 = OFF_SBUF + NBATCH*100*S2c(10)*2;
constexpr int OFF_Z2    = OFF_ZHAT2 + NBATCH*100*S2c(10)*2;
constexpr int OFF_Z     = OFF_Z2 + NBATCH*100*20*20*20;
constexpr int WS_TOTAL  = OFF_Z + NBATCH*100*32*32*32;
constexpr int OFF_HBUF  = OFF_Z2;                     // H[b][p][496][2]

__device__ __forceinline__ int S2d(int l){ return l*(2*l-1)*(2*l+1)/3; }

// ---------- init: LUTs + WMID/WOUTQ quadrature ----------
__global__ void k_lut(float* ws){
  int q = blockIdx.x*blockDim.x + threadIdx.x;
  if (q < 32){
    double bb = 16.0, s = 0.0;
    for (int k = 0; k < 16; ++k) s += sin(PI_D*(2*q+1)*(2*k+1)/(4.0*bb))/(2*k+1);
    ws[OFF_WMID+q] = (float)(2.0/bb * sin(PI_D*(2*q+1)/(4.0*bb)) * s);
  } else if (q < 52){
    int j = q - 32;
    double bb = 10.0, s = 0.0;
    for (int k = 0; k < 10; ++k) s += sin(PI_D*(2*j+1)*(2*k+1)/(4.0*bb))/(2*k+1);
    ws[OFF_WOUTQ+j] = (float)(2.0/bb * sin(PI_D*(2*j+1)/(4.0*bb)) * s);
  }
  if (q >= 1330) return;
  int l = 0; while (S2d(l+1) <= q) ++l;
  int loc = q - S2d(l), tl = 2*l+1;
  int mm = loc/tl, nn = loc%tl;
  ((int*)(ws+OFF_LUTA))[q] = 32*S2d(l) + mm*tl + nn;
  ((int*)(ws+OFF_LUTB))[q] = ((mm-l+9)*19 + (nn-l+9)) | ((tl*tl) << 9) | ((nn-l+9) << 19);
  ((int*)(ws+OFF_LUTC))[q] = (S2d(l) + mm*tl) | ((S2d(l) + nn*tl) << 11) | (tl << 22);
}

// ---------- init: Wigner-d tables ----------
__device__ double dev_wigner_t(const double* fact, int l, int mp, int m, double beta){
  double ch = cos(0.5*beta), sh = sin(0.5*beta);
  int kmin = m - mp; if (kmin < 0) kmin = 0;
  int kmax = l + m; if (l - mp < kmax) kmax = l - mp;
  double pref = sqrt(fact[l+mp]*fact[l-mp]*fact[l+m]*fact[l-m]);
  int ec = 2*l + m - mp - 2*kmin, es = mp - m + 2*kmin;
  double cp = 1.0, sp = 1.0;
  for (int e = 0; e < ec; ++e) cp *= ch;
  for (int e = 0; e < es; ++e) sp *= sh;
  double ch2i = 1.0/(ch*ch), sh2 = sh*sh;
  double sum = 0.0;
  for (int k = kmin; k <= kmax; ++k){
    double t = 1.0/(fact[l+m-k]*fact[k]*fact[l-mp-k]*fact[mp-m+k]);
    if ((mp-m+k) & 1) t = -t;
    sum += t*cp*sp;
    cp *= ch2i; sp *= sh2;
  }
  return pref*sum;
}

constexpr int N_DM0W = 60*256;
constexpr int N_DMID = 32*S2c(16);
constexpr int N_DOUT = 20*S2c(10);
constexpr int N_DEQ  = S2c(16);
constexpr int N_WIG  = N_DM0W + N_DMID + N_DOUT + N_DEQ;

__global__ void k_wigner(float* ws){
  __shared__ double fact[32];
  if (threadIdx.x == 0){ fact[0] = 1.0; for (int i = 1; i < 32; ++i) fact[i] = fact[i-1]*i; }
  __syncthreads();
  int idx = blockIdx.x*blockDim.x + threadIdx.x;
  if (idx >= N_WIG) return;
  if (idx < N_DM0W){
    int l = 0; while (60*(l+1)*(l+1) <= idx) ++l;
    int rem = idx - 60*l*l, tl = 2*l+1;
    int p = rem/tl, mm = rem%tl;
    double beta = (p+0.5)*PI_D/60.0;
    double s = 0.0;
    for (int k = 0; k < 30; ++k) s += sin(PI_D*(2*p+1)*(2*k+1)/120.0)/(2*k+1);
    double w_in = (2.0/30.0) * sin(PI_D*(2*p+1)/120.0) * s;
    ws[OFF_DM0W+idx] = (float)(dev_wigner_t(fact, l, mm-l, 0, beta) * w_in);
    return;
  }
  idx -= N_DM0W;
  if (idx < N_DMID){
    int l = 0; while (32*S2d(l+1) <= idx) ++l;
    int rem = idx - 32*S2d(l), tl = 2*l+1;
    int q = rem % (tl*tl), p = rem/(tl*tl);
    int mm = q/tl, nn = q%tl;
    double beta = (p+0.5)*PI_D/32.0;
    ws[OFF_DMID+idx] = (float)dev_wigner_t(fact, l, mm-l, nn-l, beta);
    return;
  }
  idx -= N_DMID;
  if (idx < N_DOUT){
    int l = 0; while (20*S2d(l+1) <= idx) ++l;
    int rem = idx - 20*S2d(l), tl = 2*l+1;
    int q = rem % (tl*tl), p = rem/(tl*tl);
    int mm = q/tl, nn = q%tl;
    double beta = (p+0.5)*PI_D/20.0;
    ws[OFF_DOUT+idx] = (float)dev_wigner_t(fact, l, mm-l, nn-l, beta);
    return;
  }
  idx -= N_DOUT;
  {
    int l = 0; while (S2d(l+1) <= idx) ++l;
    int rem = idx - S2d(l), tl = 2*l+1;
    int mm = rem/tl, nn = rem%tl;
    ws[OFF_DEQ+idx] = (float)dev_wigner_t(fact, l, mm-l, nn-l, 0.5*PI_D);
  }
}

// ---------- 1. projection ----------
__global__ void k_project(const float* __restrict__ x, float* ws){
  int t = blockIdx.x*blockDim.x + threadIdx.x;
  if (t >= NBATCH*NPTS) return;
  int b = t / NPTS, n = t % NPTS;
  const float* xb = x + (size_t)b*3*NPTS;
  float xx = xb[n], yy = xb[NPTS+n], zz = xb[2*NPTS+n];
  float r = sqrtf(xx*xx + yy*yy + zz*zz + 1e-12f);
  float ct = zz / r;
  ct = fminf(fmaxf(ct, -1.0f + 1e-7f), 1.0f - 1e-7f);
  float beta = acosf(ct);
  float alpha = atan2f(yy, xx);
  if (alpha < 0.0f) alpha += 2.0f*(float)PI_D;
  int jb = (int)((beta / (float)PI_D) * 60.0f);
  jb = jb < 0 ? 0 : (jb > 59 ? 59 : jb);
  int ja = (int)((alpha / (2.0f*(float)PI_D)) * 60.0f);
  ja = ja < 0 ? 0 : (ja > 59 ? 59 : ja);
  unsigned* img = (unsigned*)(ws + OFF_IMG) + (b*3600 + jb*60 + ja);
  atomicMax(img, __float_as_uint(r));
}

// ---------- 2. S2 DFT over alpha ----------
__global__ void k_s2dft(float* ws){
  int t = blockIdx.x*blockDim.x + threadIdx.x;
  if (t >= NBATCH*60*31) return;
  int b = t/(60*31), r = t%(60*31);
  int p = r/31, mi = r%31, m = mi - 15;
  const float* img = ws + OFF_IMG + (b*60 + p)*60;
  float sr = 0.f, si = 0.f;
  for (int a = 0; a < 60; ++a){
    int k = ((a*m) % 60 + 60) % 60;
    float c = cospif(k/30.0f), s = sinpif(k/30.0f);
    float v = img[a];
    sr += v*c; si -= v*s;
  }
  ws[OFF_XF + t*2]   = sr;
  ws[OFF_XF + t*2+1] = si;
}

// ---------- 3. xhat ----------
__global__ void k_xhat(float* ws){
  int t = blockIdx.x*blockDim.x + threadIdx.x;
  if (t >= NBATCH*256) return;
  int b = t/256, flat = t%256;
  int l = 0; while ((l+1)*(l+1) <= flat) ++l;
  int mm = flat - l*l, tl = 2*l+1;
  int mi = mm - l + 15;
  float sr = 0.f, si = 0.f;
  for (int p = 0; p < 60; ++p){
    float w = ws[OFF_DM0W + 60*l*l + p*tl + mm];
    sr += w * ws[OFF_XF + ((b*60+p)*31 + mi)*2];
    si += w * ws[OFF_XF + ((b*60+p)*31 + mi)*2 + 1];
  }
  ws[OFF_XHAT + t*2]   = sr;
  ws[OFF_XHAT + t*2+1] = si;
}

// ---------- 3b. Ws2 ----------
__global__ void k_ws2(float* ws, const float* __restrict__ w_s2, float scale1){
  int t = blockIdx.x*blockDim.x + threadIdx.x;
  if (t >= 100*31) return;
  int o = t/31, ni = t%31, n = ni - 15;
  float sr = 0.f, si = 0.f;
  for (int k = 0; k < 60; ++k){
    int kk = ((k*n) % 60 + 60) % 60;
    float c = cospif(kk/30.0f), s = sinpif(kk/30.0f);
    float v = w_s2[o*60 + k] * scale1;
    sr += v*c; si += v*s;
  }
  ws[OFF_WS2 + t*2]   = sr;
  ws[OFF_WS2 + t*2+1] = si;
}

// ---------- 3c. H[b][p][m][ni] + fused spectral stats ----------
__global__ __launch_bounds__(256) void k_H(float* ws){
  int bid = blockIdx.x;                // b*32+p
  int p = bid & 31, b = bid >> 5;
  __shared__ float xh[512], Dt[256], G[31];
  __shared__ int dbase[16];
  int tid = threadIdx.x;
  {
    int flat = tid;
    int l = 0; while ((l+1)*(l+1) <= flat) ++l;
    int mm = flat - l*l, tl = 2*l+1;
    xh[2*flat]   = ws[OFF_XHAT + (b*256+flat)*2];
    xh[2*flat+1] = ws[OFF_XHAT + (b*256+flat)*2+1];
    Dt[flat] = (float)tl * ws[OFF_DEQ + S2d(l) + mm*tl + l];
  }
  if (tid < 31) G[tid] = 0.f;
  if (tid < 16){ int l = tid, tl = 2*l+1; dbase[l] = OFF_DMID + 32*S2d(l) + p*tl*tl; }
  __syncthreads();
  float* Hb = ws + OFF_HBUF + (size_t)bid*992;
  for (int q = tid; q < 496; q += 256){
    int m = q/31, ni = q%31, n = ni-15;
    int an = n < 0 ? -n : n;
    int lmin = m > an ? m : an;
    float ar = 0.f, ai = 0.f;
    for (int l = lmin; l < 16; ++l){
      int tl = 2*l+1;
      float d = ws[dbase[l] + (m+l)*tl + (n+l)];
      float t = d * Dt[l*l + (n+l)];
      int fa = l*l + (m+l);
      ar += t*xh[2*fa]; ai += t*xh[2*fa+1];
    }
    Hb[2*q] = ar; Hb[2*q+1] = ai;
    float w = (q < 31) ? 1.f : 2.f;
    atomicAdd(&G[ni], w*(ar*ar + ai*ai));
    if (q == 15){
      atomicAdd(&ws[OFF_GT + 31], ar);
      atomicAdd(&ws[OFF_GT + 32], ai);
    }
  }
  __syncthreads();
  if (tid < 31) atomicAdd(&ws[OFF_GT + tid], G[tid]);
}

// ---------- 3e. BN1 coefficients from spectral stats ----------
__global__ void k_bnfin1(float* ws, const float* __restrict__ g1, const float* __restrict__ be1,
                         const float* __restrict__ b_s2){
  int t = threadIdx.x;
  if (t >= 100) return;
  float ssq = 0.f;
  for (int ni = 0; ni < 31; ++ni){
    float wr = ws[OFF_WS2 + (t*31+ni)*2], wi = ws[OFF_WS2 + (t*31+ni)*2+1];
    ssq += (wr*wr + wi*wi) * ws[OFF_GT + ni];
  }
  float wr15 = ws[OFF_WS2 + (t*31+15)*2], wi15 = ws[OFF_WS2 + (t*31+15)*2+1];
  float f00 = wr15*ws[OFF_GT+31] - wi15*ws[OFF_GT+32];
  float bsv = b_s2[t];
  const float invN = 1.0f/262144.0f;
  float mu  = f00*invN + bsv;
  float Ez2 = ssq*(invN/1024.0f) + 2.f*bsv*f00*invN + bsv*bsv;
  float var = Ez2 - mu*mu;
  float sA = rsqrtf(var + 1e-5f) * g1[t];
  ws[OFF_BN1AB+t]     = sA;
  ws[OFF_BN1AB+100+t] = be1[t] - mu*sA;
}

// ---------- 4. FUSED: zhat->IFFT->BN+ReLU->fwd 2D DFT -> X2w (SoA LDS layout) ----------
// A[1216]: phases 1-2: Fg SoA (Ar=A[q], Ai=A[608+q], q<496)
//          phase 3-4:  y at stride 36 (A[0..1147])
//          phases 5-7: t1 SoA (t1r=A[idx], t1i=A[608+idx], idx<608)
// B[1216]: phases 2-3: tmpS SoA, m-stride 37 (Br=B[m*37+g], Bi=B[608+m*37+g])
//          phases 4-5: Bs 4 class-planes of [a*9+g2] at offsets c*304
__global__ __launch_bounds__(256) void k_fused(float* ws, const float* __restrict__ b_s2){
  int bid = blockIdx.x;                 // (b*100+o)*32+p
  int p = bid & 31, bo = bid >> 5;
  int o = bo % F1C, b = bo / F1C;
  __shared__ float A[1216], B[1216];
  __shared__ float twr[32], twi[32], Wr[31], Wi[31];
  int tid = threadIdx.x;
  if (tid < 32){ twr[tid] = cospif(tid/16.0f); twi[tid] = sinpif(tid/16.0f); }
  if (tid < 31){ Wr[tid] = ws[OFF_WS2 + (o*31+tid)*2]; Wi[tid] = ws[OFF_WS2 + (o*31+tid)*2+1]; }
  float sA = ws[OFF_BN1AB+o], sB = ws[OFF_BN1AB+100+o];
  float bsv = b_s2[o];
  __syncthreads();
  // ---- phase 1: Fg = W*H -> A SoA
  {
    const float* Hb = ws + OFF_HBUF + (size_t)((b<<5)|p)*992;
    for (int q = tid; q < 496; q += 256){
      int ni = q % 31;
      float hr = Hb[2*q], hi = Hb[2*q+1];
      A[q]     = hr*Wr[ni] - hi*Wi[ni];
      A[608+q] = hr*Wi[ni] + hi*Wr[ni];
    }
  }
  __syncthreads();
  // ---- phase 2: alpha radix-4 (A SoA -> B tmpS SoA, m-stride 37)
  if (tid < 128){
    int m = tid >> 3, g0 = tid & 7;
    float T0r=0,T0i=0,T1r=0,T1i=0,T2r=0,T2i=0,T3r=0,T3i=0;
    int base = m*31;
    #pragma unroll
    for (int ni = 0; ni < 31; ++ni){
      int k = ((ni-15)*g0) & 31;
      float c = twr[k], s = twi[k];
      float fr = A[base+ni], fi = A[608+base+ni];
      float re = fr*c - fi*s, im = fr*s + fi*c;
      int cc = (ni+1) & 3;
      if (cc == 0){ T0r += re; T0i += im; }
      else if (cc == 1){ T1r += re; T1i += im; }
      else if (cc == 2){ T2r += re; T2i += im; }
      else { T3r += re; T3i += im; }
    }
    float Ar=T0r+T2r, Ai=T0i+T2i, Br=T0r-T2r, Bi=T0i-T2i;
    float Cr=T1r+T3r, Ci=T1i+T3i, Dr=T1r-T3r, Di=T1i-T3i;
    int ix = m*37 + g0;
    B[ix]        = Ar+Cr; B[608+ix]      = Ai+Ci;   // s=0
    B[ix+8]      = Br-Di; B[608+ix+8]    = Bi+Dr;   // s=1
    B[ix+16]     = Ar-Cr; B[608+ix+16]   = Ai-Ci;   // s=2
    B[ix+24]     = Br+Di; B[608+ix+24]   = Bi-Dr;   // s=3
  }
  __syncthreads();
  // ---- phase 3: gamma radix-4 + bias + BN + ReLU -> y in A (stride 36)
  {
    int a0 = tid >> 5, g = tid & 31;
    float U0r=0, U2r=0, U1r=0, U1i=0, U3r=0, U3i=0;
    #pragma unroll
    for (int m = 1; m < 16; ++m){
      int k = (m*a0) & 31;
      float c = twr[k], s = twi[k];
      float tr = B[m*37+g], ti = B[608+m*37+g];
      float re = tr*c - ti*s;
      int cc = m & 3;
      if (cc == 0) U0r += re;
      else if (cc == 2) U2r += re;
      else {
        float im = tr*s + ti*c;
        if (cc == 1){ U1r += re; U1i += im; }
        else        { U3r += re; U3i += im; }
      }
    }
    float Ar = U0r + U2r, Br = U0r - U2r;
    float Cr = U1r + U3r, Di = U1i - U3i;
    float t0 = B[g];
    float v0 = ((t0 + 2.0f*(Ar + Cr))*(1.0f/1024.0f) + bsv)*sA + sB;
    float v1 = ((t0 + 2.0f*(Br - Di))*(1.0f/1024.0f) + bsv)*sA + sB;
    float v2 = ((t0 + 2.0f*(Ar - Cr))*(1.0f/1024.0f) + bsv)*sA + sB;
    float v3 = ((t0 + 2.0f*(Br + Di))*(1.0f/1024.0f) + bsv)*sA + sB;
    A[(a0     )*36 + g] = v0 > 0.f ? v0 : 0.f;
    A[(a0 +  8)*36 + g] = v1 > 0.f ? v1 : 0.f;
    A[(a0 + 16)*36 + g] = v2 > 0.f ? v2 : 0.f;
    A[(a0 + 24)*36 + g] = v3 > 0.f ? v3 : 0.f;
  }
  __syncthreads();
  // ---- phase 4: radix-4 prep over g (A(y,stride36) -> B class-planes [a*9+g2] @ c*304)
  {
    int a = tid >> 3, g2 = tid & 7;
    float y0 = A[a*36+g2], y1 = A[a*36+g2+8], y2 = A[a*36+g2+16], y3 = A[a*36+g2+24];
    float e = y0+y2, f = y1+y3;
    int ix = a*9 + g2;
    B[ix]         = e+f;          // c0   plane 0
    B[304+ix]     = e-f;          // c2   plane 1
    B[608+ix]     = y0-y2;        // c1r  plane 2
    B[912+ix]     = -(y1-y3);     // c1i  plane 3
  }
  __syncthreads();
  // ---- phase 5: pass1 (B planes -> A t1 SoA), ni=9..18
  for (int q = tid; q < 320; q += 256){
    int a = q/10, n = q%10, ni = 9+n;
    int c = n & 3;
    int ixb = a*9;
    float sr = 0.f, si = 0.f;
    if ((c & 1) == 0){
      const float* P = B + (c >> 1)*304 + ixb;
      #pragma unroll
      for (int g2 = 0; g2 < 8; ++g2){
        int k = (g2*n) & 31;
        float Bv = P[g2];
        sr += Bv*twr[k]; si -= Bv*twi[k];
      }
    } else {
      float sgn = (c == 1) ? 1.f : -1.f;
      const float* Pr = B + 608 + ixb;
      const float* Pi = B + 912 + ixb;
      #pragma unroll
      for (int g2 = 0; g2 < 8; ++g2){
        int k = (g2*n) & 31;
        float cc_ = twr[k], ss = twi[k];
        float br = Pr[g2], bi = sgn*Pi[g2];
        sr += br*cc_ + bi*ss;
        si += bi*cc_ - br*ss;
      }
    }
    A[a*19+ni]       = sr;
    A[608 + a*19+ni] = si;
  }
  __syncthreads();
  // ---- phase 6: butterfly over a (t1 SoA in A), ni=9..18
  for (int q = tid; q < 160; q += 256){
    int a = q/10, ni = 9 + q%10;
    int i0 = a*19+ni, i1 = (a+16)*19+ni;
    float xr=A[i0], xi=A[608+i0], yr=A[i1], yi=A[608+i1];
    A[i0]=xr+yr; A[608+i0]=xi+yi; A[i1]=xr-yr; A[608+i1]=xi-yi;
  }
  __syncthreads();
  // ---- phase 7: pass3 -> X2w (722 floats) to global
  float wm = ws[OFF_WMID+p];
  float* zp = ws + OFF_Z + (size_t)bid*1024;
  for (int q = tid; q < 190; q += 256){
    int m = q/10 - 9, nio = q%10, ni = 9+nio;
    int off = (m & 1) ? 16*19 : 0;
    float sr = 0.f, si = 0.f;
    for (int a = 0; a < 16; ++a){
      int k = (a*m) & 31;
      float c = twr[k], s = twi[k];
      int ix = off + a*19 + ni;
      float tr = A[ix], ti = A[608+ix];
      sr += tr*c + ti*s;
      si += ti*c - tr*s;
    }
    sr *= wm; si *= wm;
    int qf = (m+9)*19 + ni;
    zp[2*qf] = sr; zp[2*qf+1] = si;
    if (nio > 0){
      int qm = (9-m)*19 + (9-nio);
      zp[2*qm] = sr; zp[2*qm+1] = -si;
    }
  }
}

// ---------- 6b. Wigner beta-projection + fused d_eq transform -> S, 512 threads, dbuf ----------
__global__ __launch_bounds__(512) void k_so3fft_b(float* ws){
  int bo = blockIdx.x;
  int tid = threadIdx.x;
  __shared__ float xw[2][722];
  __shared__ float xh2[2660];
  const float* xwbase = ws + OFF_Z + (size_t)bo*32*1024;
  const int* lutA = (const int*)(ws + OFF_LUTA);
  const int* lutB = (const int*)(ws + OFF_LUTB);
  const int* lutC = (const int*)(ws + OFF_LUTC);
  float accr[3], acci[3];
  int addr[3], xi2[3], tl2v[3];
  #pragma unroll
  for (int j = 0; j < 3; ++j){
    accr[j] = 0.f; acci[j] = 0.f;
    int q = tid + 512*j;
    if (q < 1330){ addr[j] = OFF_DMID + lutA[q]; int lb = lutB[q]; xi2[j] = 2*(lb & 511); tl2v[j] = (lb >> 9) & 1023; }
    else { addr[j] = OFF_DMID; xi2[j] = 0; tl2v[j] = 0; }
  }
  for (int u = tid; u < 722; u += 512) xw[0][u] = xwbase[u];
  __syncthreads();
  for (int pp = 0; pp < 32; ++pp){
    int cur = pp & 1;
    if (pp + 1 < 32){
      const float* src = xwbase + (size_t)(pp+1)*1024;
      for (int u = tid; u < 722; u += 512) xw[cur^1][u] = src[u];
    }
    #pragma unroll
    for (int j = 0; j < 3; ++j){
      int q = tid + 512*j;
      if (q < 1330){
        float d = ws[addr[j]];
        accr[j] += d*xw[cur][xi2[j]]; acci[j] += d*xw[cur][xi2[j]+1];
        addr[j] += tl2v[j];
      }
    }
    __syncthreads();
  }
  #pragma unroll
  for (int j = 0; j < 3; ++j){
    int q = tid + 512*j;
    if (q < 1330){ xh2[2*q] = accr[j]; xh2[2*q+1] = acci[j]; }
  }
  __syncthreads();
  #pragma unroll
  for (int j = 0; j < 3; ++j){
    int q = tid + 512*j;
    if (q < 1330){
      int lc = lutC[q];
      int rowstart = lc & 2047, deqrow = (lc >> 11) & 2047, tl = lc >> 22;
      const float* dq = ws + OFF_DEQ + deqrow;
      const float* xb = xh2 + 2*rowstart;
      float sr = 0.f, si = 0.f;
      for (int k = 0; k < tl; ++k){
        float d = dq[k];
        sr += d*xb[2*k]; si += d*xb[2*k+1];
      }
      int base = OFF_SBUF + (bo*1330 + q)*2;
      ws[base]   = sr;
      ws[base+1] = si;
    }
  }
}

// ---------- 7a. W[i][o][ni] ----------
__global__ void k_wconv(float* ws, const float* __restrict__ w_so3, float scale2){
  int t = blockIdx.x*blockDim.x + threadIdx.x;
  if (t >= 100*100*19) return;
  int ni = t % 19, io = t / 19;
  int n = ni - 9;
  float sr = 0.f, si = 0.f;
  for (int j = 0; j < 32; ++j){
    int k = (j*n) & 31;
    float c = cospif(k/16.0f), s = sinpif(k/16.0f);
    float v = w_so3[io*32 + j] * scale2;
    sr += v*c; si += v*s;
  }
  ws[OFF_WCONV + t*2]   = sr;
  ws[OFF_WCONV + t*2+1] = si;
}

// ---------- 7c. zhat2 = S . W over i: 4 o's per thread ----------
__global__ void k_zhat2(float* ws){
  int t = blockIdx.x*blockDim.x + threadIdx.x;
  if (t >= NBATCH*25*1330) return;
  int q = t % 1330, boo = t / 1330;
  int oq = boo % 25, b = boo / 25;
  int o0 = oq*4;
  int lb = ((const int*)(ws+OFF_LUTB))[q];
  int ni = (lb >> 19) & 31;
  const float* sp  = ws + OFF_SBUF + (size_t)(b*100)*2660 + 2*q;
  const float* wp0 = ws + OFF_WCONV + (size_t)(o0*19 + ni)*2;
  const float* wp1 = wp0 + 38;
  const float* wp2 = wp0 + 76;
  const float* wp3 = wp0 + 114;
  float sr0=0,si0=0,sr1=0,si1=0,sr2=0,si2=0,sr3=0,si3=0;
  for (int i = 0; i < 100; ++i){
    float Sr = sp[0], Si = sp[1];
    float W0r = wp0[0], W0i = wp0[1];
    float W1r = wp1[0], W1i = wp1[1];
    float W2r = wp2[0], W2i = wp2[1];
    float W3r = wp3[0], W3i = wp3[1];
    sr0 += Sr*W0r - Si*W0i; si0 += Sr*W0i + Si*W0r;
    sr1 += Sr*W1r - Si*W1i; si1 += Sr*W1i + Si*W1r;
    sr2 += Sr*W2r - Si*W2i; si2 += Sr*W2i + Si*W2r;
    sr3 += Sr*W3r - Si*W3i; si3 += Sr*W3i + Si*W3r;
    sp += 2660;
    wp0 += 3800; wp1 += 3800; wp2 += 3800; wp3 += 3800;
  }
  size_t zb0 = (size_t)OFF_ZHAT2 + ((size_t)(b*100 + o0)*1330 + q)*2;
  ws[zb0]          = sr0; ws[zb0 + 1]      = si0;
  ws[zb0 + 2660]   = sr1; ws[zb0 + 2661]   = si1;
  ws[zb0 + 5320]   = sr2; ws[zb0 + 5321]   = si2;
  ws[zb0 + 7980]   = sr3; ws[zb0 + 7981]   = si3;
}

// ---------- 8. SO(3) IFFT (b=10), Hermitian + radix-2, 5 p's per block ----------
__global__ __launch_bounds__(256) void k_so3ifft_out(float* ws, const float* __restrict__ b_so3){
  int bid = blockIdx.x;                 // (b*100+o)*4 + pg
  int pg = bid % 4, bo = bid / 4;
  int o = bo % F2C, b = bo / F2C;
  __shared__ __align__(16) float zh[2660];
  __shared__ float Fg[380], tmpS[400];
  __shared__ float twr[20], twi[20], redA[4], redB[4];
  int tid = threadIdx.x;
  {
    const float4* zsrc = (const float4*)(ws + OFF_ZHAT2 + (size_t)bo*2660);
    float4* zds = (float4*)zh;
    for (int q = tid; q < 665; q += 256) zds[q] = zsrc[q];
  }
  if (tid < 20){ twr[tid] = cospif(tid/10.0f); twi[tid] = sinpif(tid/10.0f); }
  __syncthreads();
  float bsv = b_so3[o];
  float lsum = 0.f, lss = 0.f;
  float* z2 = ws + OFF_Z2;
  for (int pp = 0; pp < 5; ++pp){
    int p = pg*5 + pp;
    for (int q = tid; q < 190; q += 256){
      int m = q/19, ni = q%19, n = ni-9;
      int an = n < 0 ? -n : n;
      int lmin = m > an ? m : an;
      float ar = 0.f, ai = 0.f;
      for (int l = lmin; l < 10; ++l){
        int tl = 2*l+1;
        float d = ws[OFF_DOUT + 20*S2d(l) + (p*tl + (m+l))*tl + (n+l)] * (float)tl;
        int fz = S2d(l) + (m+l)*tl + (n+l);
        ar += d*zh[2*fz]; ai += d*zh[2*fz+1];
      }
      Fg[2*q] = ar; Fg[2*q+1] = ai;
    }
    __syncthreads();
    for (int q = tid; q < 100; q += 256){
      int m = q/10, g = q%10;
      float Er=0.f, Ei=0.f, Or=0.f, Oi=0.f;
      int base = 2*m*19;
      for (int ni = 1; ni < 19; ni += 2){
        int n = ni-9;
        int k = ((n*g) % 20 + 20) % 20;
        float c = twr[k], s = twi[k];
        float fr = Fg[base+2*ni], fi = Fg[base+2*ni+1];
        Er += fr*c - fi*s; Ei += fr*s + fi*c;
      }
      for (int ni = 0; ni < 19; ni += 2){
        int n = ni-9;
        int k = ((n*g) % 20 + 20) % 20;
        float c = twr[k], s = twi[k];
        float fr = Fg[base+2*ni], fi = Fg[base+2*ni+1];
        Or += fr*c - fi*s; Oi += fr*s + fi*c;
      }
      tmpS[2*(m*20+g)]      = Er+Or; tmpS[2*(m*20+g)+1]      = Ei+Oi;
      tmpS[2*(m*20+g+10)]   = Er-Or; tmpS[2*(m*20+g+10)+1]   = Ei-Oi;
    }
    __syncthreads();
    size_t zb = ((size_t)bo*20 + p)*400;
    for (int q = tid; q < 200; q += 256){
      int a = q/20, g = q%20;
      float E = 0.f, O = 0.f;
      for (int m = 2; m < 10; m += 2){
        int k = (m*a) % 20;
        E += tmpS[2*(m*20+g)]*twr[k] - tmpS[2*(m*20+g)+1]*twi[k];
      }
      for (int m = 1; m < 10; m += 2){
        int k = (m*a) % 20;
        O += tmpS[2*(m*20+g)]*twr[k] - tmpS[2*(m*20+g)+1]*twi[k];
      }
      float t0 = tmpS[2*g];
      float v1 = (t0 + 2.0f*(E+O))*(1.0f/400.0f) + bsv;
      float v2 = (t0 + 2.0f*(E-O))*(1.0f/400.0f) + bsv;
      z2[zb + a*20 + g]       = v1;
      z2[zb + (a+10)*20 + g]  = v2;
      lsum += v1+v2; lss += v1*v1+v2*v2;
    }
    __syncthreads();
  }
  for (int off = 32; off; off >>= 1){ lsum += __shfl_down(lsum, off); lss += __shfl_down(lss, off); }
  if ((tid & 63) == 0){ redA[tid>>6] = lsum; redB[tid>>6] = lss; }
  __syncthreads();
  if (tid == 0){
    atomicAdd(&ws[OFF_BN2 + o],       redA[0]+redA[1]+redA[2]+redA[3]);
    atomicAdd(&ws[OFF_BN2 + 100 + o], redB[0]+redB[1]+redB[2]+redB[3]);
  }
}

__global__ void k_bnfin2(float* ws, const float* __restrict__ g2, const float* __restrict__ be2){
  int t = threadIdx.x;
  if (t >= 100) return;
  const float invN = 1.0f/64000.0f;
  float mu = ws[OFF_BN2+t]*invN;
  float var = ws[OFF_BN2+100+t]*invN - mu*mu;
  float sA = rsqrtf(var + 1e-5f) * g2[t];
  ws[OFF_BN2AB+t]     = sA;
  ws[OFF_BN2AB+100+t] = be2[t] - mu*sA;
}

// ---------- 9. final pooling (float4) ----------
__global__ __launch_bounds__(256) void k_final(float* ws, float* __restrict__ out){
  int bid = blockIdx.x;
  int c = bid % 100, b = bid / 100;
  int tid = threadIdx.x;
  float sA = ws[OFF_BN2AB+c], sB = ws[OFF_BN2AB+100+c];
  const float4* z2 = (const float4*)(ws + OFF_Z2 + (size_t)(b*100+c)*8000);
  float lsum = 0.f;
  for (int j = tid; j < 2000; j += 256){
    int p = j / 100;
    float wq = ws[OFF_WOUTQ + p];
    float4 v = z2[j];
    float t0 = v.x*sA + sB, t1 = v.y*sA + sB, t2 = v.z*sA + sB, t3 = v.w*sA + sB;
    t0 = t0 > 0.f ? t0 : 0.f;
    t1 = t1 > 0.f ? t1 : 0.f;
    t2 = t2 > 0.f ? t2 : 0.f;
    t3 = t3 > 0.f ? t3 : 0.f;
    lsum += (t0+t1+t2+t3) * wq;
  }
  for (int off = 32; off; off >>= 1) lsum += __shfl_down(lsum, off);
  __shared__ float red[4];
  if ((tid & 63) == 0) red[tid>>6] = lsum;
  __syncthreads();
  if (tid == 0) out[b*100 + c] = red[0]+red[1]+red[2]+red[3];
}

extern "C" void kernel_launch(void* const* d_in, const int* in_sizes, int n_in,
                              void* d_out, int out_size, void* d_ws, size_t ws_size,
                              hipStream_t stream){
  const float* x      = (const float*)d_in[0];
  const float* w_s2   = (const float*)d_in[1];
  const float* b_s2   = (const float*)d_in[2];
  const float* g1     = (const float*)d_in[3];
  const float* be1    = (const float*)d_in[4];
  const float* w_so3  = (const float*)d_in[5];
  const float* b_so3  = (const float*)d_in[6];
  const float* g2     = (const float*)d_in[7];
  const float* be2    = (const float*)d_in[8];
  float* ws  = (float*)d_ws;
  float* out = (float*)d_out;

  hipMemsetAsync(ws + OFF_IMG, 0, NBATCH*3600*sizeof(float), stream);
  hipMemsetAsync(ws + OFF_BN2, 0, 200*sizeof(float), stream);
  hipMemsetAsync(ws + OFF_GT,  0, 34*sizeof(float), stream);

  k_lut<<<6, 256, 0, stream>>>(ws);
  k_wigner<<<(N_WIG + 255)/256, 256, 0, stream>>>(ws);
  k_project<<<(NBATCH*NPTS + 255)/256, 256, 0, stream>>>(x, ws);
  k_s2dft<<<(NBATCH*60*31 + 255)/256, 256, 0, stream>>>(ws);
  k_xhat<<<(NBATCH*256 + 255)/256, 256, 0, stream>>>(ws);
  float scale1 = (float)(1.0/sqrt(60.0*1.0*65536.0/900.0));
  k_ws2<<<(100*31 + 255)/256, 256, 0, stream>>>(ws, w_s2, scale1);
  k_H<<<NBATCH*32, 256, 0, stream>>>(ws);
  k_bnfin1<<<1, 128, 0, stream>>>(ws, g1, be1, b_s2);
  k_fused<<<NBATCH*F1C*32, 256, 0, stream>>>(ws, b_s2);
  k_so3fft_b<<<NBATCH*F1C, 512, 0, stream>>>(ws);
  float scale2 = (float)(1.0/sqrt(32.0*100.0*1000.0/4096.0));
  k_wconv<<<(100*100*19 + 255)/256, 256, 0, stream>>>(ws, w_so3, scale2);
  k_zhat2<<<(NBATCH*25*1330 + 255)/256, 256, 0, stream>>>(ws);
  k_so3ifft_out<<<NBATCH*F2C*4, 256, 0, stream>>>(ws, b_so3);
  k_bnfin2<<<1, 128, 0, stream>>>(ws, g2, be2);
  k_final<<<NBATCH*100, 256, 0, stream>>>(ws, out);
}

// Round 20
// 438.834 us; speedup vs baseline: 1.0277x; 1.0277x over previous
//
#include <hip/hip_runtime.h>
#include <math.h>

#define PI_D 3.14159265358979323846

constexpr int NBATCH = 8;
constexpr int NPTS   = 2048;
constexpr int F1C    = 100;
constexpr int F2C    = 100;

__host__ __device__ constexpr int S2c(int l){ return l*(2*l-1)*(2*l+1)/3; }

// ---- workspace layout (float offsets) ----
constexpr int OFF_WIN   = 0;
constexpr int OFF_WMID  = OFF_WIN + 60;
constexpr int OFF_WOUTQ = OFF_WMID + 32;
constexpr int OFF_DM0W  = OFF_WOUTQ + 20;
constexpr int OFF_DMID  = OFF_DM0W + 60*256;
constexpr int OFF_DOUT  = OFF_DMID + 32*S2c(16);
constexpr int OFF_DEQ   = OFF_DOUT + 20*S2c(10);
constexpr int OFF_IMG   = OFF_DEQ + S2c(16);
constexpr int OFF_XF    = OFF_IMG + NBATCH*60*60;
constexpr int OFF_XHAT  = OFF_XF + NBATCH*60*31*2;
constexpr int OFF_WS2   = OFF_XHAT + NBATCH*256*2;
constexpr int OFF_BN1   = OFF_WS2 + 100*31*2;
constexpr int OFF_BN1AB = OFF_BN1 + 200;
constexpr int OFF_BN2   = OFF_BN1AB + 200;
constexpr int OFF_BN2AB = OFF_BN2 + 200;
constexpr int OFF_LUTA  = OFF_BN2AB + 200;
constexpr int OFF_LUTB  = OFF_LUTA + 1330;
constexpr int OFF_LUTC  = OFF_LUTB + 1330;
constexpr int OFF_GT    = OFF_LUTC + 1330;            // 34: Gtot[31], Htot r/i
constexpr int OFF_WCONV = OFF_GT + 34;                // W[i][o][ni][2]
constexpr int OFF_XHAT2 = OFF_WCONV + 100*100*19*2;
constexpr int OFF_SBUF  = OFF_XHAT2 + NBATCH*100*S2c(10)*2;  // S[b][i][q][2]
constexpr int OFF_ZHAT2 = OFF_SBUF + NBATCH*100*S2c(10)*2;
constexpr int OFF_Z2    = OFF_ZHAT2 + NBATCH*100*S2c(10)*2;
constexpr int OFF_Z     = OFF_Z2 + NBATCH*100*20*20*20;
constexpr int WS_TOTAL  = OFF_Z + NBATCH*100*32*32*32;
constexpr int OFF_HBUF  = OFF_Z2;                     // H[b][p][496][2]

__device__ __forceinline__ int S2d(int l){ return l*(2*l-1)*(2*l+1)/3; }

// ---------- init: LUTs + WMID/WOUTQ quadrature ----------
__global__ void k_lut(float* ws){
  int q = blockIdx.x*blockDim.x + threadIdx.x;
  if (q < 32){
    double bb = 16.0, s = 0.0;
    for (int k = 0; k < 16; ++k) s += sin(PI_D*(2*q+1)*(2*k+1)/(4.0*bb))/(2*k+1);
    ws[OFF_WMID+q] = (float)(2.0/bb * sin(PI_D*(2*q+1)/(4.0*bb)) * s);
  } else if (q < 52){
    int j = q - 32;
    double bb = 10.0, s = 0.0;
    for (int k = 0; k < 10; ++k) s += sin(PI_D*(2*j+1)*(2*k+1)/(4.0*bb))/(2*k+1);
    ws[OFF_WOUTQ+j] = (float)(2.0/bb * sin(PI_D*(2*j+1)/(4.0*bb)) * s);
  }
  if (q >= 1330) return;
  int l = 0; while (S2d(l+1) <= q) ++l;
  int loc = q - S2d(l), tl = 2*l+1;
  int mm = loc/tl, nn = loc%tl;
  ((int*)(ws+OFF_LUTA))[q] = 32*S2d(l) + mm*tl + nn;
  ((int*)(ws+OFF_LUTB))[q] = ((mm-l+9)*19 + (nn-l+9)) | ((tl*tl) << 9) | ((nn-l+9) << 19);
  ((int*)(ws+OFF_LUTC))[q] = (S2d(l) + mm*tl) | ((S2d(l) + nn*tl) << 11) | (tl << 22);
}

// ---------- init: Wigner-d tables ----------
__device__ double dev_wigner_t(const double* fact, int l, int mp, int m, double beta){
  double ch = cos(0.5*beta), sh = sin(0.5*beta);
  int kmin = m - mp; if (kmin < 0) kmin = 0;
  int kmax = l + m; if (l - mp < kmax) kmax = l - mp;
  double pref = sqrt(fact[l+mp]*fact[l-mp]*fact[l+m]*fact[l-m]);
  int ec = 2*l + m - mp - 2*kmin, es = mp - m + 2*kmin;
  double cp = 1.0, sp = 1.0;
  for (int e = 0; e < ec; ++e) cp *= ch;
  for (int e = 0; e < es; ++e) sp *= sh;
  double ch2i = 1.0/(ch*ch), sh2 = sh*sh;
  double sum = 0.0;
  for (int k = kmin; k <= kmax; ++k){
    double t = 1.0/(fact[l+m-k]*fact[k]*fact[l-mp-k]*fact[mp-m+k]);
    if ((mp-m+k) & 1) t = -t;
    sum += t*cp*sp;
    cp *= ch2i; sp *= sh2;
  }
  return pref*sum;
}

constexpr int N_DM0W = 60*256;
constexpr int N_DMID = 32*S2c(16);
constexpr int N_DOUT = 20*S2c(10);
constexpr int N_DEQ  = S2c(16);
constexpr int N_WIG  = N_DM0W + N_DMID + N_DOUT + N_DEQ;

__global__ void k_wigner(float* ws){
  __shared__ double fact[32];
  if (threadIdx.x == 0){ fact[0] = 1.0; for (int i = 1; i < 32; ++i) fact[i] = fact[i-1]*i; }
  __syncthreads();
  int idx = blockIdx.x*blockDim.x + threadIdx.x;
  if (idx >= N_WIG) return;
  if (idx < N_DM0W){
    int l = 0; while (60*(l+1)*(l+1) <= idx) ++l;
    int rem = idx - 60*l*l, tl = 2*l+1;
    int p = rem/tl, mm = rem%tl;
    double beta = (p+0.5)*PI_D/60.0;
    double s = 0.0;
    for (int k = 0; k < 30; ++k) s += sin(PI_D*(2*p+1)*(2*k+1)/120.0)/(2*k+1);
    double w_in = (2.0/30.0) * sin(PI_D*(2*p+1)/120.0) * s;
    ws[OFF_DM0W+idx] = (float)(dev_wigner_t(fact, l, mm-l, 0, beta) * w_in);
    return;
  }
  idx -= N_DM0W;
  if (idx < N_DMID){
    int l = 0; while (32*S2d(l+1) <= idx) ++l;
    int rem = idx - 32*S2d(l), tl = 2*l+1;
    int q = rem % (tl*tl), p = rem/(tl*tl);
    int mm = q/tl, nn = q%tl;
    double beta = (p+0.5)*PI_D/32.0;
    ws[OFF_DMID+idx] = (float)dev_wigner_t(fact, l, mm-l, nn-l, beta);
    return;
  }
  idx -= N_DMID;
  if (idx < N_DOUT){
    int l = 0; while (20*S2d(l+1) <= idx) ++l;
    int rem = idx - 20*S2d(l), tl = 2*l+1;
    int q = rem % (tl*tl), p = rem/(tl*tl);
    int mm = q/tl, nn = q%tl;
    double beta = (p+0.5)*PI_D/20.0;
    ws[OFF_DOUT+idx] = (float)dev_wigner_t(fact, l, mm-l, nn-l, beta);
    return;
  }
  idx -= N_DOUT;
  {
    int l = 0; while (S2d(l+1) <= idx) ++l;
    int rem = idx - S2d(l), tl = 2*l+1;
    int mm = rem/tl, nn = rem%tl;
    ws[OFF_DEQ+idx] = (float)dev_wigner_t(fact, l, mm-l, nn-l, 0.5*PI_D);
  }
}

// ---------- 1. projection ----------
__global__ void k_project(const float* __restrict__ x, float* ws){
  int t = blockIdx.x*blockDim.x + threadIdx.x;
  if (t >= NBATCH*NPTS) return;
  int b = t / NPTS, n = t % NPTS;
  const float* xb = x + (size_t)b*3*NPTS;
  float xx = xb[n], yy = xb[NPTS+n], zz = xb[2*NPTS+n];
  float r = sqrtf(xx*xx + yy*yy + zz*zz + 1e-12f);
  float ct = zz / r;
  ct = fminf(fmaxf(ct, -1.0f + 1e-7f), 1.0f - 1e-7f);
  float beta = acosf(ct);
  float alpha = atan2f(yy, xx);
  if (alpha < 0.0f) alpha += 2.0f*(float)PI_D;
  int jb = (int)((beta / (float)PI_D) * 60.0f);
  jb = jb < 0 ? 0 : (jb > 59 ? 59 : jb);
  int ja = (int)((alpha / (2.0f*(float)PI_D)) * 60.0f);
  ja = ja < 0 ? 0 : (ja > 59 ? 59 : ja);
  unsigned* img = (unsigned*)(ws + OFF_IMG) + (b*3600 + jb*60 + ja);
  atomicMax(img, __float_as_uint(r));
}

// ---------- 2. S2 DFT over alpha ----------
__global__ void k_s2dft(float* ws){
  int t = blockIdx.x*blockDim.x + threadIdx.x;
  if (t >= NBATCH*60*31) return;
  int b = t/(60*31), r = t%(60*31);
  int p = r/31, mi = r%31, m = mi - 15;
  const float* img = ws + OFF_IMG + (b*60 + p)*60;
  float sr = 0.f, si = 0.f;
  for (int a = 0; a < 60; ++a){
    int k = ((a*m) % 60 + 60) % 60;
    float c = cospif(k/30.0f), s = sinpif(k/30.0f);
    float v = img[a];
    sr += v*c; si -= v*s;
  }
  ws[OFF_XF + t*2]   = sr;
  ws[OFF_XF + t*2+1] = si;
}

// ---------- 3. xhat ----------
__global__ void k_xhat(float* ws){
  int t = blockIdx.x*blockDim.x + threadIdx.x;
  if (t >= NBATCH*256) return;
  int b = t/256, flat = t%256;
  int l = 0; while ((l+1)*(l+1) <= flat) ++l;
  int mm = flat - l*l, tl = 2*l+1;
  int mi = mm - l + 15;
  float sr = 0.f, si = 0.f;
  for (int p = 0; p < 60; ++p){
    float w = ws[OFF_DM0W + 60*l*l + p*tl + mm];
    sr += w * ws[OFF_XF + ((b*60+p)*31 + mi)*2];
    si += w * ws[OFF_XF + ((b*60+p)*31 + mi)*2 + 1];
  }
  ws[OFF_XHAT + t*2]   = sr;
  ws[OFF_XHAT + t*2+1] = si;
}

// ---------- 3b. Ws2 ----------
__global__ void k_ws2(float* ws, const float* __restrict__ w_s2, float scale1){
  int t = blockIdx.x*blockDim.x + threadIdx.x;
  if (t >= 100*31) return;
  int o = t/31, ni = t%31, n = ni - 15;
  float sr = 0.f, si = 0.f;
  for (int k = 0; k < 60; ++k){
    int kk = ((k*n) % 60 + 60) % 60;
    float c = cospif(kk/30.0f), s = sinpif(kk/30.0f);
    float v = w_s2[o*60 + k] * scale1;
    sr += v*c; si += v*s;
  }
  ws[OFF_WS2 + t*2]   = sr;
  ws[OFF_WS2 + t*2+1] = si;
}

// ---------- 3c. H[b][p][m][ni] + fused spectral stats ----------
__global__ __launch_bounds__(256) void k_H(float* ws){
  int bid = blockIdx.x;                // b*32+p
  int p = bid & 31, b = bid >> 5;
  __shared__ float xh[512], Dt[256], G[31];
  __shared__ int dbase[16];
  int tid = threadIdx.x;
  {
    int flat = tid;
    int l = 0; while ((l+1)*(l+1) <= flat) ++l;
    int mm = flat - l*l, tl = 2*l+1;
    xh[2*flat]   = ws[OFF_XHAT + (b*256+flat)*2];
    xh[2*flat+1] = ws[OFF_XHAT + (b*256+flat)*2+1];
    Dt[flat] = (float)tl * ws[OFF_DEQ + S2d(l) + mm*tl + l];
  }
  if (tid < 31) G[tid] = 0.f;
  if (tid < 16){ int l = tid, tl = 2*l+1; dbase[l] = OFF_DMID + 32*S2d(l) + p*tl*tl; }
  __syncthreads();
  float* Hb = ws + OFF_HBUF + (size_t)bid*992;
  for (int q = tid; q < 496; q += 256){
    int m = q/31, ni = q%31, n = ni-15;
    int an = n < 0 ? -n : n;
    int lmin = m > an ? m : an;
    float ar = 0.f, ai = 0.f;
    for (int l = lmin; l < 16; ++l){
      int tl = 2*l+1;
      float d = ws[dbase[l] + (m+l)*tl + (n+l)];
      float t = d * Dt[l*l + (n+l)];
      int fa = l*l + (m+l);
      ar += t*xh[2*fa]; ai += t*xh[2*fa+1];
    }
    Hb[2*q] = ar; Hb[2*q+1] = ai;
    float w = (q < 31) ? 1.f : 2.f;
    atomicAdd(&G[ni], w*(ar*ar + ai*ai));
    if (q == 15){
      atomicAdd(&ws[OFF_GT + 31], ar);
      atomicAdd(&ws[OFF_GT + 32], ai);
    }
  }
  __syncthreads();
  if (tid < 31) atomicAdd(&ws[OFF_GT + tid], G[tid]);
}

// ---------- 3e. BN1 coefficients from spectral stats ----------
__global__ void k_bnfin1(float* ws, const float* __restrict__ g1, const float* __restrict__ be1,
                         const float* __restrict__ b_s2){
  int t = threadIdx.x;
  if (t >= 100) return;
  float ssq = 0.f;
  for (int ni = 0; ni < 31; ++ni){
    float wr = ws[OFF_WS2 + (t*31+ni)*2], wi = ws[OFF_WS2 + (t*31+ni)*2+1];
    ssq += (wr*wr + wi*wi) * ws[OFF_GT + ni];
  }
  float wr15 = ws[OFF_WS2 + (t*31+15)*2], wi15 = ws[OFF_WS2 + (t*31+15)*2+1];
  float f00 = wr15*ws[OFF_GT+31] - wi15*ws[OFF_GT+32];
  float bsv = b_s2[t];
  const float invN = 1.0f/262144.0f;
  float mu  = f00*invN + bsv;
  float Ez2 = ssq*(invN/1024.0f) + 2.f*bsv*f00*invN + bsv*bsv;
  float var = Ez2 - mu*mu;
  float sA = rsqrtf(var + 1e-5f) * g1[t];
  ws[OFF_BN1AB+t]     = sA;
  ws[OFF_BN1AB+100+t] = be1[t] - mu*sA;
}

// ---------- 4. FUSED: zhat->IFFT->BN+ReLU->fwd 2D DFT -> X2w (R16 layout: y stride 36) ----------
__global__ __launch_bounds__(256) void k_fused(float* ws, const float* __restrict__ b_s2){
  int bid = blockIdx.x;                 // (b*100+o)*32+p
  int p = bid & 31, bo = bid >> 5;
  int o = bo % F1C, b = bo / F1C;
  __shared__ float A[1216], B[1152];
  __shared__ float twr[32], twi[32], Wr[31], Wi[31];
  int tid = threadIdx.x;
  if (tid < 32){ twr[tid] = cospif(tid/16.0f); twi[tid] = sinpif(tid/16.0f); }
  if (tid < 31){ Wr[tid] = ws[OFF_WS2 + (o*31+tid)*2]; Wi[tid] = ws[OFF_WS2 + (o*31+tid)*2+1]; }
  float sA = ws[OFF_BN1AB+o], sB = ws[OFF_BN1AB+100+o];
  float bsv = b_s2[o];
  __syncthreads();
  // ---- phase 1: Fg = W*H -> A[0..991]
  {
    const float* Hb = ws + OFF_HBUF + (size_t)((b<<5)|p)*992;
    for (int q = tid; q < 496; q += 256){
      int ni = q % 31;
      float hr = Hb[2*q], hi = Hb[2*q+1];
      A[2*q]   = hr*Wr[ni] - hi*Wi[ni];
      A[2*q+1] = hr*Wi[ni] + hi*Wr[ni];
    }
  }
  __syncthreads();
  // ---- phase 2: alpha radix-4 (A -> B as tmpS[1024])
  if (tid < 128){
    int m = tid >> 3, g0 = tid & 7;
    float T0r=0,T0i=0,T1r=0,T1i=0,T2r=0,T2i=0,T3r=0,T3i=0;
    int base = 2*m*31;
    #pragma unroll
    for (int ni = 0; ni < 31; ++ni){
      int k = ((ni-15)*g0) & 31;
      float c = twr[k], s = twi[k];
      float fr = A[base+2*ni], fi = A[base+2*ni+1];
      float re = fr*c - fi*s, im = fr*s + fi*c;
      int cc = (ni+1) & 3;
      if (cc == 0){ T0r += re; T0i += im; }
      else if (cc == 1){ T1r += re; T1i += im; }
      else if (cc == 2){ T2r += re; T2i += im; }
      else { T3r += re; T3i += im; }
    }
    float Ar=T0r+T2r, Ai=T0i+T2i, Br=T0r-T2r, Bi=T0i-T2i;
    float Cr=T1r+T3r, Ci=T1i+T3i, Dr=T1r-T3r, Di=T1i-T3i;
    int ix = 2*(m*32+g0);
    B[ix]      = Ar+Cr; B[ix+1]    = Ai+Ci;
    B[ix+16]   = Br-Di; B[ix+17]   = Bi+Dr;
    B[ix+32]   = Ar-Cr; B[ix+33]   = Ai-Ci;
    B[ix+48]   = Br+Di; B[ix+49]   = Bi-Dr;
  }
  __syncthreads();
  // ---- phase 3: gamma radix-4 + bias + BN + ReLU -> y in A (stride 36)
  {
    int a0 = tid >> 5, g = tid & 31;
    float U0r=0, U2r=0, U1r=0, U1i=0, U3r=0, U3i=0;
    #pragma unroll
    for (int m = 1; m < 16; ++m){
      int k = (m*a0) & 31;
      float c = twr[k], s = twi[k];
      float tr = B[2*(m*32+g)], ti = B[2*(m*32+g)+1];
      float re = tr*c - ti*s;
      int cc = m & 3;
      if (cc == 0) U0r += re;
      else if (cc == 2) U2r += re;
      else {
        float im = tr*s + ti*c;
        if (cc == 1){ U1r += re; U1i += im; }
        else        { U3r += re; U3i += im; }
      }
    }
    float Ar = U0r + U2r, Br = U0r - U2r;
    float Cr = U1r + U3r, Di = U1i - U3i;
    float t0 = B[2*g];
    float v0 = ((t0 + 2.0f*(Ar + Cr))*(1.0f/1024.0f) + bsv)*sA + sB;
    float v1 = ((t0 + 2.0f*(Br - Di))*(1.0f/1024.0f) + bsv)*sA + sB;
    float v2 = ((t0 + 2.0f*(Ar - Cr))*(1.0f/1024.0f) + bsv)*sA + sB;
    float v3 = ((t0 + 2.0f*(Br + Di))*(1.0f/1024.0f) + bsv)*sA + sB;
    A[(a0     )*36 + g] = v0 > 0.f ? v0 : 0.f;
    A[(a0 +  8)*36 + g] = v1 > 0.f ? v1 : 0.f;
    A[(a0 + 16)*36 + g] = v2 > 0.f ? v2 : 0.f;
    A[(a0 + 24)*36 + g] = v3 > 0.f ? v3 : 0.f;
  }
  __syncthreads();
  // ---- phase 4: radix-4 prep over g (A(y,stride36) -> B(Bs,stride36))
  {
    int a = tid >> 3, g2 = tid & 7;
    float y0 = A[a*36+g2], y1 = A[a*36+g2+8], y2 = A[a*36+g2+16], y3 = A[a*36+g2+24];
    float e = y0+y2, f = y1+y3;
    int bb = a*36 + g2*4;
    B[bb]   = e+f;
    B[bb+1] = e-f;
    B[bb+2] = y0-y2;
    B[bb+3] = -(y1-y3);
  }
  __syncthreads();
  // ---- phase 5: pass1 (B(Bs) -> A(t1)), ni=9..18
  for (int q = tid; q < 320; q += 256){
    int a = q/10, n = q%10, ni = 9+n;
    int c = n & 3;
    int bb = a*36;
    float sr = 0.f, si = 0.f;
    if ((c & 1) == 0){
      int off = bb + (c >> 1);
      #pragma unroll
      for (int g2 = 0; g2 < 8; ++g2){
        int k = (g2*n) & 31;
        float Bv = B[off + g2*4];
        sr += Bv*twr[k]; si -= Bv*twi[k];
      }
    } else {
      float sgn = (c == 1) ? 1.f : -1.f;
      #pragma unroll
      for (int g2 = 0; g2 < 8; ++g2){
        int k = (g2*n) & 31;
        float cc_ = twr[k], ss = twi[k];
        float br = B[bb+g2*4+2], bi = sgn*B[bb+g2*4+3];
        sr += br*cc_ + bi*ss;
        si += bi*cc_ - br*ss;
      }
    }
    A[2*(a*19+ni)] = sr; A[2*(a*19+ni)+1] = si;
  }
  __syncthreads();
  // ---- phase 6: butterfly over a (in A), ni=9..18
  for (int q = tid; q < 160; q += 256){
    int a = q/10, ni = 9 + q%10;
    int i0 = 2*(a*19+ni), i1 = 2*((a+16)*19+ni);
    float xr=A[i0], xi=A[i0+1], yr=A[i1], yi=A[i1+1];
    A[i0]=xr+yr; A[i0+1]=xi+yi; A[i1]=xr-yr; A[i1+1]=xi-yi;
  }
  __syncthreads();
  // ---- phase 7: pass3 -> X2w (722 floats) to global
  float wm = ws[OFF_WMID+p];
  float* zp = ws + OFF_Z + (size_t)bid*1024;
  for (int q = tid; q < 190; q += 256){
    int m = q/10 - 9, nio = q%10, ni = 9+nio;
    int off = (m & 1) ? 16*19 : 0;
    float sr = 0.f, si = 0.f;
    for (int a = 0; a < 16; ++a){
      int k = (a*m) & 31;
      float c = twr[k], s = twi[k];
      float tr = A[2*(off+a*19+ni)], ti = A[2*(off+a*19+ni)+1];
      sr += tr*c + ti*s;
      si += ti*c - tr*s;
    }
    sr *= wm; si *= wm;
    int qf = (m+9)*19 + ni;
    zp[2*qf] = sr; zp[2*qf+1] = si;
    if (nio > 0){
      int qm = (9-m)*19 + (9-nio);
      zp[2*qm] = sr; zp[2*qm+1] = -si;
    }
  }
}

// ---------- 6b. Wigner beta-projection + fused d_eq transform -> S, 512 threads, dbuf ----------
__global__ __launch_bounds__(512) void k_so3fft_b(float* ws){
  int bo = blockIdx.x;
  int tid = threadIdx.x;
  __shared__ float xw[2][722];
  __shared__ float xh2[2660];
  const float* xwbase = ws + OFF_Z + (size_t)bo*32*1024;
  const int* lutA = (const int*)(ws + OFF_LUTA);
  const int* lutB = (const int*)(ws + OFF_LUTB);
  const int* lutC = (const int*)(ws + OFF_LUTC);
  float accr[3], acci[3];
  int addr[3], xi2[3], tl2v[3];
  #pragma unroll
  for (int j = 0; j < 3; ++j){
    accr[j] = 0.f; acci[j] = 0.f;
    int q = tid + 512*j;
    if (q < 1330){ addr[j] = OFF_DMID + lutA[q]; int lb = lutB[q]; xi2[j] = 2*(lb & 511); tl2v[j] = (lb >> 9) & 1023; }
    else { addr[j] = OFF_DMID; xi2[j] = 0; tl2v[j] = 0; }
  }
  for (int u = tid; u < 722; u += 512) xw[0][u] = xwbase[u];
  __syncthreads();
  for (int pp = 0; pp < 32; ++pp){
    int cur = pp & 1;
    if (pp + 1 < 32){
      const float* src = xwbase + (size_t)(pp+1)*1024;
      for (int u = tid; u < 722; u += 512) xw[cur^1][u] = src[u];
    }
    #pragma unroll
    for (int j = 0; j < 3; ++j){
      int q = tid + 512*j;
      if (q < 1330){
        float d = ws[addr[j]];
        accr[j] += d*xw[cur][xi2[j]]; acci[j] += d*xw[cur][xi2[j]+1];
        addr[j] += tl2v[j];
      }
    }
    __syncthreads();
  }
  #pragma unroll
  for (int j = 0; j < 3; ++j){
    int q = tid + 512*j;
    if (q < 1330){ xh2[2*q] = accr[j]; xh2[2*q+1] = acci[j]; }
  }
  __syncthreads();
  #pragma unroll
  for (int j = 0; j < 3; ++j){
    int q = tid + 512*j;
    if (q < 1330){
      int lc = lutC[q];
      int rowstart = lc & 2047, deqrow = (lc >> 11) & 2047, tl = lc >> 22;
      const float* dq = ws + OFF_DEQ + deqrow;
      const float* xb = xh2 + 2*rowstart;
      float sr = 0.f, si = 0.f;
      for (int k = 0; k < tl; ++k){
        float d = dq[k];
        sr += d*xb[2*k]; si += d*xb[2*k+1];
      }
      int base = OFF_SBUF + (bo*1330 + q)*2;
      ws[base]   = sr;
      ws[base+1] = si;
    }
  }
}

// ---------- 7a. W[i][o][ni] ----------
__global__ void k_wconv(float* ws, const float* __restrict__ w_so3, float scale2){
  int t = blockIdx.x*blockDim.x + threadIdx.x;
  if (t >= 100*100*19) return;
  int ni = t % 19, io = t / 19;
  int n = ni - 9;
  float sr = 0.f, si = 0.f;
  for (int j = 0; j < 32; ++j){
    int k = (j*n) & 31;
    float c = cospif(k/16.0f), s = sinpif(k/16.0f);
    float v = w_so3[io*32 + j] * scale2;
    sr += v*c; si += v*s;
  }
  ws[OFF_WCONV + t*2]   = sr;
  ws[OFF_WCONV + t*2+1] = si;
}

// ---------- 7c. zhat2 = S . W over i: 4 o's per thread ----------
__global__ void k_zhat2(float* ws){
  int t = blockIdx.x*blockDim.x + threadIdx.x;
  if (t >= NBATCH*25*1330) return;
  int q = t % 1330, boo = t / 1330;
  int oq = boo % 25, b = boo / 25;
  int o0 = oq*4;
  int lb = ((const int*)(ws+OFF_LUTB))[q];
  int ni = (lb >> 19) & 31;
  const float* sp  = ws + OFF_SBUF + (size_t)(b*100)*2660 + 2*q;
  const float* wp0 = ws + OFF_WCONV + (size_t)(o0*19 + ni)*2;
  const float* wp1 = wp0 + 38;
  const float* wp2 = wp0 + 76;
  const float* wp3 = wp0 + 114;
  float sr0=0,si0=0,sr1=0,si1=0,sr2=0,si2=0,sr3=0,si3=0;
  for (int i = 0; i < 100; ++i){
    float Sr = sp[0], Si = sp[1];
    float W0r = wp0[0], W0i = wp0[1];
    float W1r = wp1[0], W1i = wp1[1];
    float W2r = wp2[0], W2i = wp2[1];
    float W3r = wp3[0], W3i = wp3[1];
    sr0 += Sr*W0r - Si*W0i; si0 += Sr*W0i + Si*W0r;
    sr1 += Sr*W1r - Si*W1i; si1 += Sr*W1i + Si*W1r;
    sr2 += Sr*W2r - Si*W2i; si2 += Sr*W2i + Si*W2r;
    sr3 += Sr*W3r - Si*W3i; si3 += Sr*W3i + Si*W3r;
    sp += 2660;
    wp0 += 3800; wp1 += 3800; wp2 += 3800; wp3 += 3800;
  }
  size_t zb0 = (size_t)OFF_ZHAT2 + ((size_t)(b*100 + o0)*1330 + q)*2;
  ws[zb0]          = sr0; ws[zb0 + 1]      = si0;
  ws[zb0 + 2660]   = sr1; ws[zb0 + 2661]   = si1;
  ws[zb0 + 5320]   = sr2; ws[zb0 + 5321]   = si2;
  ws[zb0 + 7980]   = sr3; ws[zb0 + 7981]   = si3;
}

// ---------- 8. SO(3) IFFT (b=10), Hermitian + radix-2, 5 p's per block ----------
__global__ __launch_bounds__(256) void k_so3ifft_out(float* ws, const float* __restrict__ b_so3){
  int bid = blockIdx.x;                 // (b*100+o)*4 + pg
  int pg = bid % 4, bo = bid / 4;
  int o = bo % F2C, b = bo / F2C;
  __shared__ __align__(16) float zh[2660];
  __shared__ float Fg[380], tmpS[400];
  __shared__ float twr[20], twi[20], redA[4], redB[4];
  int tid = threadIdx.x;
  {
    const float4* zsrc = (const float4*)(ws + OFF_ZHAT2 + (size_t)bo*2660);
    float4* zds = (float4*)zh;
    for (int q = tid; q < 665; q += 256) zds[q] = zsrc[q];
  }
  if (tid < 20){ twr[tid] = cospif(tid/10.0f); twi[tid] = sinpif(tid/10.0f); }
  __syncthreads();
  float bsv = b_so3[o];
  float lsum = 0.f, lss = 0.f;
  float* z2 = ws + OFF_Z2;
  for (int pp = 0; pp < 5; ++pp){
    int p = pg*5 + pp;
    for (int q = tid; q < 190; q += 256){
      int m = q/19, ni = q%19, n = ni-9;
      int an = n < 0 ? -n : n;
      int lmin = m > an ? m : an;
      float ar = 0.f, ai = 0.f;
      for (int l = lmin; l < 10; ++l){
        int tl = 2*l+1;
        float d = ws[OFF_DOUT + 20*S2d(l) + (p*tl + (m+l))*tl + (n+l)] * (float)tl;
        int fz = S2d(l) + (m+l)*tl + (n+l);
        ar += d*zh[2*fz]; ai += d*zh[2*fz+1];
      }
      Fg[2*q] = ar; Fg[2*q+1] = ai;
    }
    __syncthreads();
    for (int q = tid; q < 100; q += 256){
      int m = q/10, g = q%10;
      float Er=0.f, Ei=0.f, Or=0.f, Oi=0.f;
      int base = 2*m*19;
      for (int ni = 1; ni < 19; ni += 2){
        int n = ni-9;
        int k = ((n*g) % 20 + 20) % 20;
        float c = twr[k], s = twi[k];
        float fr = Fg[base+2*ni], fi = Fg[base+2*ni+1];
        Er += fr*c - fi*s; Ei += fr*s + fi*c;
      }
      for (int ni = 0; ni < 19; ni += 2){
        int n = ni-9;
        int k = ((n*g) % 20 + 20) % 20;
        float c = twr[k], s = twi[k];
        float fr = Fg[base+2*ni], fi = Fg[base+2*ni+1];
        Or += fr*c - fi*s; Oi += fr*s + fi*c;
      }
      tmpS[2*(m*20+g)]      = Er+Or; tmpS[2*(m*20+g)+1]      = Ei+Oi;
      tmpS[2*(m*20+g+10)]   = Er-Or; tmpS[2*(m*20+g+10)+1]   = Ei-Oi;
    }
    __syncthreads();
    size_t zb = ((size_t)bo*20 + p)*400;
    for (int q = tid; q < 200; q += 256){
      int a = q/20, g = q%20;
      float E = 0.f, O = 0.f;
      for (int m = 2; m < 10; m += 2){
        int k = (m*a) % 20;
        E += tmpS[2*(m*20+g)]*twr[k] - tmpS[2*(m*20+g)+1]*twi[k];
      }
      for (int m = 1; m < 10; m += 2){
        int k = (m*a) % 20;
        O += tmpS[2*(m*20+g)]*twr[k] - tmpS[2*(m*20+g)+1]*twi[k];
      }
      float t0 = tmpS[2*g];
      float v1 = (t0 + 2.0f*(E+O))*(1.0f/400.0f) + bsv;
      float v2 = (t0 + 2.0f*(E-O))*(1.0f/400.0f) + bsv;
      z2[zb + a*20 + g]       = v1;
      z2[zb + (a+10)*20 + g]  = v2;
      lsum += v1+v2; lss += v1*v1+v2*v2;
    }
    __syncthreads();
  }
  for (int off = 32; off; off >>= 1){ lsum += __shfl_down(lsum, off); lss += __shfl_down(lss, off); }
  if ((tid & 63) == 0){ redA[tid>>6] = lsum; redB[tid>>6] = lss; }
  __syncthreads();
  if (tid == 0){
    atomicAdd(&ws[OFF_BN2 + o],       redA[0]+redA[1]+redA[2]+redA[3]);
    atomicAdd(&ws[OFF_BN2 + 100 + o], redB[0]+redB[1]+redB[2]+redB[3]);
  }
}

__global__ void k_bnfin2(float* ws, const float* __restrict__ g2, const float* __restrict__ be2){
  int t = threadIdx.x;
  if (t >= 100) return;
  const float invN = 1.0f/64000.0f;
  float mu = ws[OFF_BN2+t]*invN;
  float var = ws[OFF_BN2+100+t]*invN - mu*mu;
  float sA = rsqrtf(var + 1e-5f) * g2[t];
  ws[OFF_BN2AB+t]     = sA;
  ws[OFF_BN2AB+100+t] = be2[t] - mu*sA;
}

// ---------- 9. final pooling (float4) ----------
__global__ __launch_bounds__(256) void k_final(float* ws, float* __restrict__ out){
  int bid = blockIdx.x;
  int c = bid % 100, b = bid / 100;
  int tid = threadIdx.x;
  float sA = ws[OFF_BN2AB+c], sB = ws[OFF_BN2AB+100+c];
  const float4* z2 = (const float4*)(ws + OFF_Z2 + (size_t)(b*100+c)*8000);
  float lsum = 0.f;
  for (int j = tid; j < 2000; j += 256){
    int p = j / 100;
    float wq = ws[OFF_WOUTQ + p];
    float4 v = z2[j];
    float t0 = v.x*sA + sB, t1 = v.y*sA + sB, t2 = v.z*sA + sB, t3 = v.w*sA + sB;
    t0 = t0 > 0.f ? t0 : 0.f;
    t1 = t1 > 0.f ? t1 : 0.f;
    t2 = t2 > 0.f ? t2 : 0.f;
    t3 = t3 > 0.f ? t3 : 0.f;
    lsum += (t0+t1+t2+t3) * wq;
  }
  for (int off = 32; off; off >>= 1) lsum += __shfl_down(lsum, off);
  __shared__ float red[4];
  if ((tid & 63) == 0) red[tid>>6] = lsum;
  __syncthreads();
  if (tid == 0) out[b*100 + c] = red[0]+red[1]+red[2]+red[3];
}

extern "C" void kernel_launch(void* const* d_in, const int* in_sizes, int n_in,
                              void* d_out, int out_size, void* d_ws, size_t ws_size,
                              hipStream_t stream){
  const float* x      = (const float*)d_in[0];
  const float* w_s2   = (const float*)d_in[1];
  const float* b_s2   = (const float*)d_in[2];
  const float* g1     = (const float*)d_in[3];
  const float* be1    = (const float*)d_in[4];
  const float* w_so3  = (const float*)d_in[5];
  const float* b_so3  = (const float*)d_in[6];
  const float* g2     = (const float*)d_in[7];
  const float* be2    = (const float*)d_in[8];
  float* ws  = (float*)d_ws;
  float* out = (float*)d_out;

  hipMemsetAsync(ws + OFF_IMG, 0, NBATCH*3600*sizeof(float), stream);
  hipMemsetAsync(ws + OFF_BN2, 0, 200*sizeof(float), stream);
  hipMemsetAsync(ws + OFF_GT,  0, 34*sizeof(float), stream);

  k_lut<<<6, 256, 0, stream>>>(ws);
  k_wigner<<<(N_WIG + 255)/256, 256, 0, stream>>>(ws);
  k_project<<<(NBATCH*NPTS + 255)/256, 256, 0, stream>>>(x, ws);
  k_s2dft<<<(NBATCH*60*31 + 255)/256, 256, 0, stream>>>(ws);
  k_xhat<<<(NBATCH*256 + 255)/256, 256, 0, stream>>>(ws);
  float scale1 = (float)(1.0/sqrt(60.0*1.0*65536.0/900.0));
  k_ws2<<<(100*31 + 255)/256, 256, 0, stream>>>(ws, w_s2, scale1);
  k_H<<<NBATCH*32, 256, 0, stream>>>(ws);
  k_bnfin1<<<1, 128, 0, stream>>>(ws, g1, be1, b_s2);
  k_fused<<<NBATCH*F1C*32, 256, 0, stream>>>(ws, b_s2);
  k_so3fft_b<<<NBATCH*F1C, 512, 0, stream>>>(ws);
  float scale2 = (float)(1.0/sqrt(32.0*100.0*1000.0/4096.0));
  k_wconv<<<(100*100*19 + 255)/256, 256, 0, stream>>>(ws, w_so3, scale2);
  k_zhat2<<<(NBATCH*25*1330 + 255)/256, 256, 0, stream>>>(ws);
  k_so3ifft_out<<<NBATCH*F2C*4, 256, 0, stream>>>(ws, b_so3);
  k_bnfin2<<<1, 128, 0, stream>>>(ws, g2, be2);
  k_final<<<NBATCH*100, 256, 0, stream>>>(ws, out);
}